// Round 7
// baseline (701.614 us; speedup 1.0000x reference)
//
#include <hip/hip_runtime.h>
#include <hip/hip_bf16.h>
#include <math.h>

// Problem constants (B=4, S=1024, D=1024, H=16, hd=64)
#define SEQ    1024
#define DMODEL 1024
#define NHEAD  16
#define HDIM   64
#define BATCH  4
#define MROWS  4096   // B*S

typedef float f32x4 __attribute__((ext_vector_type(4)));
typedef short s16x8 __attribute__((ext_vector_type(8)));

__device__ __forceinline__ float bf2f(unsigned short u) {
    return __uint_as_float(((unsigned int)u) << 16);
}
__device__ __forceinline__ unsigned short f2bf(float f) {
    __hip_bfloat16 h = __float2bfloat16(f);   // RNE
    return *reinterpret_cast<unsigned short*>(&h);
}
// 3-way bf16 residual split: x ~= b0 + b1 + b2 (error ~ 2^-26 |x|)
__device__ __forceinline__ void split3(float x, unsigned short& u0,
                                       unsigned short& u1, unsigned short& u2) {
    u0 = f2bf(x);        float f0 = bf2f(u0);
    float r1 = x - f0;   u1 = f2bf(r1);  float f1 = bf2f(u1);
    float r2 = r1 - f1;  u2 = f2bf(r2);
}

// ---------------------------------------------------------------------------
// Input split: X[n] fp32 -> NS bf16 planes P[p][n] (row-major, same layout).
// ---------------------------------------------------------------------------
template<int NS>
__global__ __launch_bounds__(256) void splitx_k(const float* __restrict__ X,
                                                unsigned short* __restrict__ P,
                                                int nvec, size_t plane)
{
    const int i = blockIdx.x * 256 + threadIdx.x;   // 8-element vector index
    if (i >= nvec) return;
    const float* src = X + (size_t)i * 8;
    float4 v0 = *(const float4*)src;
    float4 v1 = *(const float4*)(src + 4);
    float x[8] = {v0.x, v0.y, v0.z, v0.w, v1.x, v1.y, v1.z, v1.w};
    unsigned short p0[8], p1[8], p2[8];
    #pragma unroll
    for (int e = 0; e < 8; ++e) {
        if (NS == 1) { p0[e] = f2bf(x[e]); }
        else         { split3(x[e], p0[e], p1[e], p2[e]); }
    }
    *(uint4*)(P + (size_t)i * 8) = *(uint4*)p0;
    if (NS == 3) {
        *(uint4*)(P + plane     + (size_t)i * 8) = *(uint4*)p1;
        *(uint4*)(P + 2 * plane + (size_t)i * 8) = *(uint4*)p2;
    }
}

// ---------------------------------------------------------------------------
// Weight split+transpose: W[K][N] fp32 -> NS bf16 planes Wt[p][N][K].
// ---------------------------------------------------------------------------
template<int NS>
__global__ __launch_bounds__(256) void wsplit_k(const float* __restrict__ W,
                                                unsigned short* __restrict__ Wt,
                                                size_t plane)
{
    __shared__ float tile[64][65];
    const int t  = threadIdx.x;
    const int n0 = blockIdx.x * 64;
    const int k0 = blockIdx.y * 64;
    const int col = t & 63;
    const int rq  = t >> 6;

    #pragma unroll
    for (int p = 0; p < 16; ++p) {
        const int row = p * 4 + rq;                      // k-local
        tile[row][col] = W[(size_t)(k0 + row) * DMODEL + n0 + col];
    }
    __syncthreads();
    #pragma unroll
    for (int p = 0; p < 16; ++p) {
        const int nrow = p * 4 + rq;                     // n-local
        const float v = tile[col][nrow];                 // = W[k0+col][n0+nrow]
        const size_t o = (size_t)(n0 + nrow) * DMODEL + k0 + col;
        if (NS == 1) {
            Wt[o] = f2bf(v);
        } else {
            unsigned short u0, u1, u2;
            split3(v, u0, u1, u2);
            Wt[o] = u0; Wt[plane + o] = u1; Wt[2 * plane + o] = u2;
        }
    }
}

// ---------------------------------------------------------------------------
// MFMA GEMM on pre-split bf16 planes: C = A @ W^T + bias.
// NS=1: plain bf16 -> fp32 C.  NS=3+FOLD: split-3 product, main term folded
// to fp64 every K=32 step (mask-critical Q/K).
// SPLITOUT: epilogue emits 3 bf16 planes in head layout [bh][s][64],
// value scaled by `oscale` (1/8 for Q).
// ---------------------------------------------------------------------------
template<int NS, bool FOLD, bool SPLITOUT>
__global__ __launch_bounds__(256) void gemm_planes(const unsigned short* __restrict__ Ab,
                                                   const unsigned short* __restrict__ Bb,
                                                   const float* __restrict__ biasp,
                                                   float* __restrict__ Cp,
                                                   unsigned short* __restrict__ Pout,
                                                   float oscale,
                                                   int M, int N, int K,
                                                   size_t planeA, size_t planeB,
                                                   size_t planeO)
{
    __shared__ unsigned short As[NS][64][40];
    __shared__ unsigned short Bs[NS][64][40];

    const int t = threadIdx.x;
    const int w = t >> 6, l = t & 63, g = l >> 4, j = l & 15;
    const int m0 = blockIdx.y * 64;
    const int n0 = blockIdx.x * 64;

    f32x4 facc[4] = {{0.f,0.f,0.f,0.f},{0.f,0.f,0.f,0.f},
                     {0.f,0.f,0.f,0.f},{0.f,0.f,0.f,0.f}};
    double dacc[4][4] = {};

    const int srow = t >> 2;          // 0..63
    const int scol = (t & 3) * 8;     // 0,8,16,24

    for (int k0 = 0; k0 < K; k0 += 32) {
        __syncthreads();
        #pragma unroll
        for (int p = 0; p < NS; ++p)
            *(uint4*)&As[p][srow][scol] =
                *(const uint4*)(Ab + p * planeA + (size_t)(m0 + srow) * K + k0 + scol);
        #pragma unroll
        for (int p = 0; p < NS; ++p)
            *(uint4*)&Bs[p][srow][scol] =
                *(const uint4*)(Bb + p * planeB + (size_t)(n0 + srow) * K + k0 + scol);
        __syncthreads();

        s16x8 a0 = *(const s16x8*)&As[0][w * 16 + j][g * 8];
        s16x8 a1, a2;
        if (NS == 3) {
            a1 = *(const s16x8*)&As[1][w * 16 + j][g * 8];
            a2 = *(const s16x8*)&As[2][w * 16 + j][g * 8];
        }
        #pragma unroll
        for (int ct = 0; ct < 4; ++ct) {
            s16x8 b0 = *(const s16x8*)&Bs[0][ct * 16 + j][g * 8];
            if (NS == 1) {
                facc[ct] = __builtin_amdgcn_mfma_f32_16x16x32_bf16(a0, b0, facc[ct], 0, 0, 0);
            } else {
                s16x8 b1 = *(const s16x8*)&Bs[1][ct * 16 + j][g * 8];
                s16x8 b2 = *(const s16x8*)&Bs[2][ct * 16 + j][g * 8];
                f32x4 z = {0.f, 0.f, 0.f, 0.f};
                z        = __builtin_amdgcn_mfma_f32_16x16x32_bf16(a0, b0, z,        0, 0, 0);
                facc[ct] = __builtin_amdgcn_mfma_f32_16x16x32_bf16(a0, b1, facc[ct], 0, 0, 0);
                facc[ct] = __builtin_amdgcn_mfma_f32_16x16x32_bf16(a1, b0, facc[ct], 0, 0, 0);
                facc[ct] = __builtin_amdgcn_mfma_f32_16x16x32_bf16(a1, b1, facc[ct], 0, 0, 0);
                facc[ct] = __builtin_amdgcn_mfma_f32_16x16x32_bf16(a0, b2, facc[ct], 0, 0, 0);
                facc[ct] = __builtin_amdgcn_mfma_f32_16x16x32_bf16(a2, b0, facc[ct], 0, 0, 0);
                #pragma unroll
                for (int r = 0; r < 4; ++r) dacc[ct][r] += (double)z[r];
            }
        }
    }

    #pragma unroll
    for (int ct = 0; ct < 4; ++ct) {
        const int col = n0 + ct * 16 + j;
        const float bv = biasp[col];
        #pragma unroll
        for (int r = 0; r < 4; ++r) {
            const int row = m0 + w * 16 + 4 * g + r;
            float val;
            if (FOLD) val = (float)(dacc[ct][r] + (double)facc[ct][r] + (double)bv);
            else      val = facc[ct][r] + bv;
            if (SPLITOUT) {
                const int bq = row >> 10, s = row & 1023;
                const int h  = col >> 6,  d = col & 63;
                const size_t o = (((size_t)(bq * 16 + h)) * SEQ + s) * HDIM + d;
                unsigned short u0, u1, u2;
                split3(val * oscale, u0, u1, u2);
                Pout[o] = u0; Pout[planeO + o] = u1; Pout[2 * planeO + o] = u2;
            } else {
                Cp[(size_t)row * N + col] = val;
            }
        }
    }
}

// ---------------------------------------------------------------------------
// Fused attention, two-pass streaming: pass 1 = online-softmax (m,Z) with
// zero score storage; pass 2 = recompute scores (bitwise-identical MFMA
// sequence), extract survivors + z2; phase 3 = sparse PV gather.
// Low VGPR -> high occupancy; latency-bound loads hidden by extra waves.
// ---------------------------------------------------------------------------
__global__ __launch_bounds__(256) void attn_k(const unsigned short* __restrict__ q3,
                                              const unsigned short* __restrict__ k3,
                                              const float* __restrict__ vf,
                                              unsigned short* __restrict__ attnb,
                                              size_t plane)
{
    __shared__ float redm[4][16];
    __shared__ float redz[4][16];
    __shared__ float redz2[4][16];
    __shared__ int   cnt[16];
    __shared__ int   slist[16][64];
    __shared__ float swt[16][64];

    const int t  = threadIdx.x;
    const int w  = t >> 6, l = t & 63, g = l >> 4, j = l & 15;
    const int bh = blockIdx.x >> 6;
    const int qt = blockIdx.x & 63;
    const int b  = bh >> 4, h = bh & 15;

    if (t < 16) cnt[t] = 0;

    // Q A-frags (A[m=lane&15][k=quad*8+e]); q pre-scaled by 1/8 in planes.
    s16x8 aq0[2], aq1[2], aq2[2];
    {
        const size_t qoff = ((size_t)bh * SEQ + qt * 16 + j) * HDIM + g * 8;
        #pragma unroll
        for (int half = 0; half < 2; ++half) {
            aq0[half] = *(const s16x8*)(q3 + qoff + half * 32);
            aq1[half] = *(const s16x8*)(q3 + plane + qoff + half * 32);
            aq2[half] = *(const s16x8*)(q3 + 2 * plane + qoff + half * 32);
        }
    }

    const size_t kbase = (size_t)bh * SEQ * HDIM + g * 8;
    const unsigned short* kp0 = k3 + kbase;
    const unsigned short* kp1 = kp0 + plane;
    const unsigned short* kp2 = kp0 + 2 * plane;
    const int key0 = w * 16 + j;

    // ---- pass 1: streaming scores -> online (m, Z) per row ---------------
    float rm[4], rz[4];
    #pragma unroll
    for (int r = 0; r < 4; ++r) { rm[r] = -INFINITY; rz[r] = 0.f; }

    for (int ch = 0; ch < 16; ++ch) {
        f32x4 acc0 = {0.f,0.f,0.f,0.f}, acc1 = {0.f,0.f,0.f,0.f};
        f32x4 acc2 = {0.f,0.f,0.f,0.f}, acc3 = {0.f,0.f,0.f,0.f};
        const size_t off = (size_t)(ch * 64 + key0) * HDIM;
        #pragma unroll
        for (int half = 0; half < 2; ++half) {
            const size_t o = off + half * 32;
            s16x8 b0 = *(const s16x8*)(kp0 + o);
            s16x8 b1 = *(const s16x8*)(kp1 + o);
            s16x8 b2 = *(const s16x8*)(kp2 + o);
            acc0 = __builtin_amdgcn_mfma_f32_16x16x32_bf16(aq0[half], b0, acc0, 0, 0, 0);
            acc1 = __builtin_amdgcn_mfma_f32_16x16x32_bf16(aq0[half], b1, acc1, 0, 0, 0);
            acc2 = __builtin_amdgcn_mfma_f32_16x16x32_bf16(aq1[half], b0, acc2, 0, 0, 0);
            acc3 = __builtin_amdgcn_mfma_f32_16x16x32_bf16(aq1[half], b1, acc3, 0, 0, 0);
            acc0 = __builtin_amdgcn_mfma_f32_16x16x32_bf16(aq0[half], b2, acc0, 0, 0, 0);
            acc1 = __builtin_amdgcn_mfma_f32_16x16x32_bf16(aq2[half], b0, acc1, 0, 0, 0);
        }
        #pragma unroll
        for (int r = 0; r < 4; ++r) {
            const float s  = (acc0[r] + acc2[r]) + (acc1[r] + acc3[r]);
            const float nm = fmaxf(rm[r], s);
            rz[r] = rz[r] * __expf((rm[r] - nm) * 1000.f) + __expf((s - nm) * 1000.f);
            rm[r] = nm;
        }
    }
    // merge across the 16 lanes sharing a row (xor in low 4 lane bits)
    #pragma unroll
    for (int r = 0; r < 4; ++r) {
        #pragma unroll
        for (int off = 1; off < 16; off <<= 1) {
            const float om = __shfl_xor(rm[r], off);
            const float oz = __shfl_xor(rz[r], off);
            const float nm = fmaxf(rm[r], om);
            rz[r] = rz[r] * __expf((rm[r] - nm) * 1000.f) + oz * __expf((om - nm) * 1000.f);
            rm[r] = nm;
        }
    }
    if (j == 0) {
        #pragma unroll
        for (int r = 0; r < 4; ++r) { redm[w][4 * g + r] = rm[r]; redz[w][4 * g + r] = rz[r]; }
    }
    __syncthreads();

    float  m[4];
    double cut[4];
    #pragma unroll
    for (int r = 0; r < 4; ++r) {
        const int row = 4 * g + r;
        const float m0 = redm[0][row], m1 = redm[1][row];
        const float m2 = redm[2][row], m3 = redm[3][row];
        const float mm = fmaxf(fmaxf(m0, m1), fmaxf(m2, m3));
        const float Z  = redz[0][row] * __expf((m0 - mm) * 1000.f)
                       + redz[1][row] * __expf((m1 - mm) * 1000.f)
                       + redz[2][row] * __expf((m2 - mm) * 1000.f)
                       + redz[3][row] * __expf((m3 - mm) * 1000.f);
        m[r]   = mm;
        cut[r] = (double)mm + 0.001 * log(0.019 * (double)Z);
    }

    // ---- pass 2: recompute scores, extract survivors ----------------------
    float z2p[4] = {0.f, 0.f, 0.f, 0.f};
    for (int ch = 0; ch < 16; ++ch) {
        f32x4 acc0 = {0.f,0.f,0.f,0.f}, acc1 = {0.f,0.f,0.f,0.f};
        f32x4 acc2 = {0.f,0.f,0.f,0.f}, acc3 = {0.f,0.f,0.f,0.f};
        const size_t off = (size_t)(ch * 64 + key0) * HDIM;
        #pragma unroll
        for (int half = 0; half < 2; ++half) {
            const size_t o = off + half * 32;
            s16x8 b0 = *(const s16x8*)(kp0 + o);
            s16x8 b1 = *(const s16x8*)(kp1 + o);
            s16x8 b2 = *(const s16x8*)(kp2 + o);
            acc0 = __builtin_amdgcn_mfma_f32_16x16x32_bf16(aq0[half], b0, acc0, 0, 0, 0);
            acc1 = __builtin_amdgcn_mfma_f32_16x16x32_bf16(aq0[half], b1, acc1, 0, 0, 0);
            acc2 = __builtin_amdgcn_mfma_f32_16x16x32_bf16(aq1[half], b0, acc2, 0, 0, 0);
            acc3 = __builtin_amdgcn_mfma_f32_16x16x32_bf16(aq1[half], b1, acc3, 0, 0, 0);
            acc0 = __builtin_amdgcn_mfma_f32_16x16x32_bf16(aq0[half], b2, acc0, 0, 0, 0);
            acc1 = __builtin_amdgcn_mfma_f32_16x16x32_bf16(aq2[half], b0, acc1, 0, 0, 0);
        }
        #pragma unroll
        for (int r = 0; r < 4; ++r) {
            const float s = (acc0[r] + acc2[r]) + (acc1[r] + acc3[r]);
            if ((double)s >= cut[r]) {
                const float ev = __expf(s - m[r]);
                z2p[r] += ev;
                const int row = 4 * g + r;
                const int pos = atomicAdd(&cnt[row], 1);
                if (pos < 64) {
                    slist[row][pos] = ch * 64 + key0;
                    swt[row][pos]   = ev;
                }
            }
        }
    }
    #pragma unroll
    for (int r = 0; r < 4; ++r) {
        #pragma unroll
        for (int off = 1; off < 16; off <<= 1) z2p[r] += __shfl_xor(z2p[r], off);
    }
    if (j == 0) {
        #pragma unroll
        for (int r = 0; r < 4; ++r) redz2[w][4 * g + r] = z2p[r];
    }
    __syncthreads();

    // ---- phase 3: sparse PV gather ----------------------------------------
    const float* vrow = vf + (size_t)(b * SEQ) * DMODEL + h * HDIM + l;
    #pragma unroll
    for (int rr = 0; rr < 4; ++rr) {
        const int row = 4 * w + rr;
        const int n   = cnt[row];
        float o = 0.f;
        if (n == 0) {
            for (int kk = 0; kk < SEQ; ++kk) o += vrow[(size_t)kk * DMODEL];
            o *= (1.0f / 1024.0f);
        } else if (n > 64) {
            o = INFINITY;   // capacity sentinel (cannot occur for this input)
        } else {
            const float z2 = redz2[0][row] + redz2[1][row] + redz2[2][row] + redz2[3][row];
            const float inv = 1.0f / z2;
            for (int i = 0; i < n; ++i)
                o += swt[row][i] * vrow[(size_t)slist[row][i] * DMODEL];
            o *= inv;
        }
        attnb[((size_t)(b * SEQ) + qt * 16 + row) * DMODEL + h * HDIM + l] = f2bf(o);
    }
}

// ---------------------------------------------------------------------------
extern "C" void kernel_launch(void* const* d_in, const int* in_sizes, int n_in,
                              void* d_out, int out_size, void* d_ws, size_t ws_size,
                              hipStream_t stream) {
    const float* Q  = (const float*)d_in[0];
    const float* K  = (const float*)d_in[1];
    const float* V  = (const float*)d_in[2];
    const float* Wq = (const float*)d_in[3];
    const float* bq = (const float*)d_in[4];
    const float* Wk = (const float*)d_in[5];
    const float* bk = (const float*)d_in[6];
    const float* Wv = (const float*)d_in[7];
    const float* bv = (const float*)d_in[8];
    const float* Wo = (const float*)d_in[9];
    const float* bo = (const float*)d_in[10];

    const size_t PLANE  = (size_t)MROWS * DMODEL;     // 4 Mi elements
    const size_t WPLANE = (size_t)DMODEL * DMODEL;

    unsigned short* Aspl = (unsigned short*)d_ws;      // 3*PLANE us
    unsigned short* Wp   = Aspl + 3 * PLANE;           // 3*WPLANE us
    unsigned short* q3   = Wp + 3 * WPLANE;            // 3*PLANE us
    unsigned short* k3   = q3 + 3 * PLANE;             // 3*PLANE us
    float*          vf   = (float*)(k3 + 3 * PLANE);   // PLANE f32
    unsigned short* attnb = Aspl;   // reuse after V-proj consumed Aspl

    dim3 blk(256, 1, 1);
    dim3 gg(DMODEL / 64, MROWS / 64, 1);
    dim3 gw(DMODEL / 64, DMODEL / 64, 1);
    const int nvec = (int)(PLANE / 8);
    dim3 gs((nvec + 255) / 256, 1, 1);

    // ---- Q projection -> split planes (scaled 1/8) ----
    splitx_k<3><<<gs, blk, 0, stream>>>(Q, Aspl, nvec, PLANE);
    wsplit_k<3><<<gw, blk, 0, stream>>>(Wq, Wp, WPLANE);
    gemm_planes<3, true, true><<<gg, blk, 0, stream>>>(Aspl, Wp, bq, nullptr, q3, 0.125f,
                                                       MROWS, DMODEL, DMODEL, PLANE, WPLANE, PLANE);
    // ---- K projection -> split planes ----
    splitx_k<3><<<gs, blk, 0, stream>>>(K, Aspl, nvec, PLANE);
    wsplit_k<3><<<gw, blk, 0, stream>>>(Wk, Wp, WPLANE);
    gemm_planes<3, true, true><<<gg, blk, 0, stream>>>(Aspl, Wp, bk, nullptr, k3, 1.0f,
                                                       MROWS, DMODEL, DMODEL, PLANE, WPLANE, PLANE);
    // ---- V projection (plain bf16 MFMA) -> fp32 vf ----
    splitx_k<1><<<gs, blk, 0, stream>>>(V, Aspl, nvec, PLANE);
    wsplit_k<1><<<gw, blk, 0, stream>>>(Wv, Wp, WPLANE);
    gemm_planes<1, false, false><<<gg, blk, 0, stream>>>(Aspl, Wp, bv, vf, nullptr, 1.0f,
                                                         MROWS, DMODEL, DMODEL, PLANE, WPLANE, PLANE);
    // ---- fused masked attention -> bf16 attnb ----
    attn_k<<<dim3(64 * 64, 1, 1), blk, 0, stream>>>(q3, k3, vf, attnb, PLANE);

    // ---- O projection (plain bf16 MFMA) -> fp32 d_out ----
    wsplit_k<1><<<gw, blk, 0, stream>>>(Wo, Wp, WPLANE);
    gemm_planes<1, false, false><<<gg, blk, 0, stream>>>(attnb, Wp, bo, (float*)d_out, nullptr, 1.0f,
                                                         MROWS, DMODEL, DMODEL, PLANE, WPLANE, PLANE);
}

// Round 8
// 485.086 us; speedup vs baseline: 1.4464x; 1.4464x over previous
//
#include <hip/hip_runtime.h>
#include <hip/hip_bf16.h>
#include <math.h>

// Problem constants (B=4, S=1024, D=1024, H=16, hd=64)
#define SEQ    1024
#define DMODEL 1024
#define NHEAD  16
#define HDIM   64
#define BATCH  4
#define MROWS  4096   // B*S

typedef float f32x4 __attribute__((ext_vector_type(4)));
typedef short s16x8 __attribute__((ext_vector_type(8)));

__device__ __forceinline__ float bf2f(unsigned short u) {
    return __uint_as_float(((unsigned int)u) << 16);
}
__device__ __forceinline__ unsigned short f2bf(float f) {
    __hip_bfloat16 h = __float2bfloat16(f);   // RNE
    return *reinterpret_cast<unsigned short*>(&h);
}
// 3-way bf16 residual split: x ~= b0 + b1 + b2 (error ~ 2^-26 |x|)
__device__ __forceinline__ void split3(float x, unsigned short& u0,
                                       unsigned short& u1, unsigned short& u2) {
    u0 = f2bf(x);        float f0 = bf2f(u0);
    float r1 = x - f0;   u1 = f2bf(r1);  float f1 = bf2f(u1);
    float r2 = r1 - f1;  u2 = f2bf(r2);
}

// ---------------------------------------------------------------------------
// Input split: X[n] fp32 -> NS bf16 planes P[p][n] (row-major, same layout).
// ---------------------------------------------------------------------------
template<int NS>
__global__ __launch_bounds__(256) void splitx_k(const float* __restrict__ X,
                                                unsigned short* __restrict__ P,
                                                int nvec, size_t plane)
{
    const int i = blockIdx.x * 256 + threadIdx.x;   // 8-element vector index
    if (i >= nvec) return;
    const float* src = X + (size_t)i * 8;
    float4 v0 = *(const float4*)src;
    float4 v1 = *(const float4*)(src + 4);
    float x[8] = {v0.x, v0.y, v0.z, v0.w, v1.x, v1.y, v1.z, v1.w};
    unsigned short p0[8], p1[8], p2[8];
    #pragma unroll
    for (int e = 0; e < 8; ++e) {
        if (NS == 1) { p0[e] = f2bf(x[e]); }
        else         { split3(x[e], p0[e], p1[e], p2[e]); }
    }
    *(uint4*)(P + (size_t)i * 8) = *(uint4*)p0;
    if (NS == 3) {
        *(uint4*)(P + plane     + (size_t)i * 8) = *(uint4*)p1;
        *(uint4*)(P + 2 * plane + (size_t)i * 8) = *(uint4*)p2;
    }
}

// ---------------------------------------------------------------------------
// Weight split+transpose: W[K][N] fp32 -> NS bf16 planes Wt[p][N][K].
// ---------------------------------------------------------------------------
template<int NS>
__global__ __launch_bounds__(256) void wsplit_k(const float* __restrict__ W,
                                                unsigned short* __restrict__ Wt,
                                                size_t plane)
{
    __shared__ float tile[64][65];
    const int t  = threadIdx.x;
    const int n0 = blockIdx.x * 64;
    const int k0 = blockIdx.y * 64;
    const int col = t & 63;
    const int rq  = t >> 6;

    #pragma unroll
    for (int p = 0; p < 16; ++p) {
        const int row = p * 4 + rq;                      // k-local
        tile[row][col] = W[(size_t)(k0 + row) * DMODEL + n0 + col];
    }
    __syncthreads();
    #pragma unroll
    for (int p = 0; p < 16; ++p) {
        const int nrow = p * 4 + rq;                     // n-local
        const float v = tile[col][nrow];                 // = W[k0+col][n0+nrow]
        const size_t o = (size_t)(n0 + nrow) * DMODEL + k0 + col;
        if (NS == 1) {
            Wt[o] = f2bf(v);
        } else {
            unsigned short u0, u1, u2;
            split3(v, u0, u1, u2);
            Wt[o] = u0; Wt[plane + o] = u1; Wt[2 * plane + o] = u2;
        }
    }
}

// ---------------------------------------------------------------------------
// MFMA GEMM on pre-split bf16 planes: C = A @ W^T + bias.
// NS=1: plain bf16 -> fp32 C.  NS=3+FOLD: split-3 product, main term folded
// to fp64 every K=32 step (mask-critical Q/K).
// SPLITOUT: epilogue emits 3 bf16 planes in head layout [bh][s][64],
// value scaled by `oscale` (1/8 for Q).
// ---------------------------------------------------------------------------
template<int NS, bool FOLD, bool SPLITOUT>
__global__ __launch_bounds__(256) void gemm_planes(const unsigned short* __restrict__ Ab,
                                                   const unsigned short* __restrict__ Bb,
                                                   const float* __restrict__ biasp,
                                                   float* __restrict__ Cp,
                                                   unsigned short* __restrict__ Pout,
                                                   float oscale,
                                                   int M, int N, int K,
                                                   size_t planeA, size_t planeB,
                                                   size_t planeO)
{
    __shared__ unsigned short As[NS][64][40];
    __shared__ unsigned short Bs[NS][64][40];

    const int t = threadIdx.x;
    const int w = t >> 6, l = t & 63, g = l >> 4, j = l & 15;
    const int m0 = blockIdx.y * 64;
    const int n0 = blockIdx.x * 64;

    f32x4 facc[4] = {{0.f,0.f,0.f,0.f},{0.f,0.f,0.f,0.f},
                     {0.f,0.f,0.f,0.f},{0.f,0.f,0.f,0.f}};
    double dacc[4][4] = {};

    const int srow = t >> 2;          // 0..63
    const int scol = (t & 3) * 8;     // 0,8,16,24

    for (int k0 = 0; k0 < K; k0 += 32) {
        __syncthreads();
        #pragma unroll
        for (int p = 0; p < NS; ++p)
            *(uint4*)&As[p][srow][scol] =
                *(const uint4*)(Ab + p * planeA + (size_t)(m0 + srow) * K + k0 + scol);
        #pragma unroll
        for (int p = 0; p < NS; ++p)
            *(uint4*)&Bs[p][srow][scol] =
                *(const uint4*)(Bb + p * planeB + (size_t)(n0 + srow) * K + k0 + scol);
        __syncthreads();

        s16x8 a0 = *(const s16x8*)&As[0][w * 16 + j][g * 8];
        s16x8 a1, a2;
        if (NS == 3) {
            a1 = *(const s16x8*)&As[1][w * 16 + j][g * 8];
            a2 = *(const s16x8*)&As[2][w * 16 + j][g * 8];
        }
        #pragma unroll
        for (int ct = 0; ct < 4; ++ct) {
            s16x8 b0 = *(const s16x8*)&Bs[0][ct * 16 + j][g * 8];
            if (NS == 1) {
                facc[ct] = __builtin_amdgcn_mfma_f32_16x16x32_bf16(a0, b0, facc[ct], 0, 0, 0);
            } else {
                s16x8 b1 = *(const s16x8*)&Bs[1][ct * 16 + j][g * 8];
                s16x8 b2 = *(const s16x8*)&Bs[2][ct * 16 + j][g * 8];
                f32x4 z = {0.f, 0.f, 0.f, 0.f};
                z        = __builtin_amdgcn_mfma_f32_16x16x32_bf16(a0, b0, z,        0, 0, 0);
                facc[ct] = __builtin_amdgcn_mfma_f32_16x16x32_bf16(a0, b1, facc[ct], 0, 0, 0);
                facc[ct] = __builtin_amdgcn_mfma_f32_16x16x32_bf16(a1, b0, facc[ct], 0, 0, 0);
                facc[ct] = __builtin_amdgcn_mfma_f32_16x16x32_bf16(a1, b1, facc[ct], 0, 0, 0);
                facc[ct] = __builtin_amdgcn_mfma_f32_16x16x32_bf16(a0, b2, facc[ct], 0, 0, 0);
                facc[ct] = __builtin_amdgcn_mfma_f32_16x16x32_bf16(a2, b0, facc[ct], 0, 0, 0);
                #pragma unroll
                for (int r = 0; r < 4; ++r) dacc[ct][r] += (double)z[r];
            }
        }
    }

    #pragma unroll
    for (int ct = 0; ct < 4; ++ct) {
        const int col = n0 + ct * 16 + j;
        const float bv = biasp[col];
        #pragma unroll
        for (int r = 0; r < 4; ++r) {
            const int row = m0 + w * 16 + 4 * g + r;
            float val;
            if (FOLD) val = (float)(dacc[ct][r] + (double)facc[ct][r] + (double)bv);
            else      val = facc[ct][r] + bv;
            if (SPLITOUT) {
                const int bq = row >> 10, s = row & 1023;
                const int h  = col >> 6,  d = col & 63;
                const size_t o = (((size_t)(bq * 16 + h)) * SEQ + s) * HDIM + d;
                unsigned short u0, u1, u2;
                split3(val * oscale, u0, u1, u2);
                Pout[o] = u0; Pout[planeO + o] = u1; Pout[2 * planeO + o] = u2;
            } else {
                Cp[(size_t)row * N + col] = val;
            }
        }
    }
}

// ---------------------------------------------------------------------------
// Fused attention, single-pass: 64 q-rows/block (4 waves, one 16-row q-tile
// per wave), K chunks staged once in LDS and shared by all waves.
// Online (m,Z) per row with lane-merged running max; conservative candidate
// capture (s >= nm - 0.004 superset of survivors, E[cand] ~ 7.5/row);
// exact fp64-cut prune at end; sparse PV gather.
// LDS ~44.5 KB -> 3 blocks/CU. Stride-72 K rows: 16B-aligned, conflict-free.
// ---------------------------------------------------------------------------
#define CAND 32
__global__ __launch_bounds__(256) void attn_k(const unsigned short* __restrict__ q3,
                                              const unsigned short* __restrict__ k3,
                                              const float* __restrict__ vf,
                                              unsigned short* __restrict__ attnb,
                                              size_t plane)
{
    __shared__ unsigned short Ks[3][64][72];   // 27.6 KB
    __shared__ int   ckey[64][CAND];           // 8 KB
    __shared__ float csc[64][CAND];            // 8 KB
    __shared__ int   ccnt[64];
    __shared__ float zinv[64];

    const int t  = threadIdx.x;
    const int w  = t >> 6, l = t & 63, g = l >> 4, j = l & 15;
    const int bh = blockIdx.x >> 4;     // 0..63
    const int qt = blockIdx.x & 15;     // 0..15 (64-row q groups)
    const int b  = bh >> 4, h = bh & 15;

    if (t < 64) ccnt[t] = 0;

    // A-frags for this wave's 16 q-rows (q pre-scaled 1/8 in planes)
    s16x8 aq[3][2];
    {
        const size_t qoff = ((size_t)bh * SEQ + qt * 64 + w * 16 + j) * HDIM + g * 8;
        #pragma unroll
        for (int p = 0; p < 3; ++p)
            #pragma unroll
            for (int half = 0; half < 2; ++half)
                aq[p][half] = *(const s16x8*)(q3 + p * plane + qoff + half * 32);
    }

    const int skey = t >> 2;            // staging key-local 0..63
    const int soff = (t & 3) * 16;
    const unsigned short* ksrc = k3 + (size_t)bh * (SEQ * HDIM) + (size_t)skey * HDIM + soff;

    float rm[4], rz[4];
    #pragma unroll
    for (int r = 0; r < 4; ++r) { rm[r] = -INFINITY; rz[r] = 0.f; }

    for (int ch = 0; ch < 16; ++ch) {
        __syncthreads();
        #pragma unroll
        for (int p = 0; p < 3; ++p) {
            const unsigned short* s = ksrc + p * plane + ch * 4096;
            uint4 va = *(const uint4*)(s);
            uint4 vb = *(const uint4*)(s + 8);
            *(uint4*)&Ks[p][skey][soff]     = va;
            *(uint4*)&Ks[p][skey][soff + 8] = vb;
        }
        __syncthreads();

        float sc[4][4];   // [kb][r]
        #pragma unroll
        for (int kb = 0; kb < 4; ++kb) {
            f32x4 acc0 = {0.f,0.f,0.f,0.f}, acc1 = {0.f,0.f,0.f,0.f};
            f32x4 acc2 = {0.f,0.f,0.f,0.f}, acc3 = {0.f,0.f,0.f,0.f};
            const int kr = kb * 16 + j;
            #pragma unroll
            for (int half = 0; half < 2; ++half) {
                s16x8 b0 = *(const s16x8*)&Ks[0][kr][half * 32 + g * 8];
                s16x8 b1 = *(const s16x8*)&Ks[1][kr][half * 32 + g * 8];
                s16x8 b2 = *(const s16x8*)&Ks[2][kr][half * 32 + g * 8];
                acc0 = __builtin_amdgcn_mfma_f32_16x16x32_bf16(aq[0][half], b0, acc0, 0, 0, 0);
                acc1 = __builtin_amdgcn_mfma_f32_16x16x32_bf16(aq[0][half], b1, acc1, 0, 0, 0);
                acc2 = __builtin_amdgcn_mfma_f32_16x16x32_bf16(aq[1][half], b0, acc2, 0, 0, 0);
                acc3 = __builtin_amdgcn_mfma_f32_16x16x32_bf16(aq[1][half], b1, acc3, 0, 0, 0);
                acc0 = __builtin_amdgcn_mfma_f32_16x16x32_bf16(aq[0][half], b2, acc0, 0, 0, 0);
                acc1 = __builtin_amdgcn_mfma_f32_16x16x32_bf16(aq[2][half], b0, acc1, 0, 0, 0);
            }
            #pragma unroll
            for (int r = 0; r < 4; ++r)
                sc[kb][r] = (acc0[r] + acc2[r]) + (acc1[r] + acc3[r]);
        }

        // online (m,Z) with row-global running max + candidate capture
        #pragma unroll
        for (int r = 0; r < 4; ++r) {
            float nm = fmaxf(fmaxf(sc[0][r], sc[1][r]), fmaxf(sc[2][r], sc[3][r]));
            nm = fmaxf(nm, rm[r]);
            #pragma unroll
            for (int off = 1; off < 16; off <<= 1) nm = fmaxf(nm, __shfl_xor(nm, off));
            float add = 0.f;
            #pragma unroll
            for (int kb = 0; kb < 4; ++kb) add += __expf((sc[kb][r] - nm) * 1000.f);
            rz[r] = rz[r] * __expf((rm[r] - nm) * 1000.f) + add;
            rm[r] = nm;
            const float thr = nm - 0.004f;   // cut >= m_final-0.00396 >= nm-0.00396
            #pragma unroll
            for (int kb = 0; kb < 4; ++kb) {
                if (sc[kb][r] >= thr) {
                    const int row = w * 16 + 4 * g + r;
                    const int pos = atomicAdd(&ccnt[row], 1);
                    if (pos < CAND) {
                        ckey[row][pos] = ch * 64 + kb * 16 + j;
                        csc[row][pos]  = sc[kb][r];
                    }
                }
            }
        }
    }
    __syncthreads();

    // finalize: Z reduce across 16 lanes, exact cut, prune+compact candidates
    float Zr[4];
    #pragma unroll
    for (int r = 0; r < 4; ++r) {
        float z = rz[r];
        #pragma unroll
        for (int off = 1; off < 16; off <<= 1) z += __shfl_xor(z, off);
        Zr[r] = z;
    }
    #pragma unroll
    for (int r = 0; r < 4; ++r) {
        if (j == r) {
            const int row = w * 16 + 4 * g + r;
            const double cut = (double)rm[r] + 0.001 * log(0.019 * (double)Zr[r]);
            const int craw = ccnt[row];
            const int c = craw < CAND ? craw : CAND;
            int n = 0; float z2 = 0.f;
            for (int i = 0; i < c; ++i) {
                const float s = csc[row][i];
                if ((double)s >= cut) {
                    const float ev = __expf(s - rm[r]);
                    ckey[row][n] = ckey[row][i];
                    csc[row][n]  = ev;
                    z2 += ev; ++n;
                }
            }
            ccnt[row] = (craw > CAND) ? -1 : n;   // -1 = overflow sentinel
            zinv[row] = (n > 0) ? 1.f / z2 : 0.f;
        }
    }
    __syncthreads();

    // sparse PV gather (wave w handles its own 16 rows; lane l = dim)
    const float* vbase = vf + (size_t)b * SEQ * DMODEL + h * HDIM + l;
    for (int i = 0; i < 16; ++i) {
        const int row = w * 16 + i;
        const int n = ccnt[row];
        float o = 0.f;
        if (n == 0) {
            // all masked -> uniform weights over all 1024 keys
            for (int kk = 0; kk < SEQ; ++kk) o += vbase[(size_t)kk * DMODEL];
            o *= (1.0f / 1024.0f);
        } else if (n < 0) {
            o = INFINITY;   // candidate overflow sentinel (P ~ 1e-6)
        } else {
            const float inv = zinv[row];
            for (int i2 = 0; i2 < n; ++i2)
                o += csc[row][i2] * vbase[(size_t)ckey[row][i2] * DMODEL];
            o *= inv;
        }
        attnb[((size_t)b * SEQ + qt * 64 + row) * DMODEL + h * HDIM + l] = f2bf(o);
    }
}

// ---------------------------------------------------------------------------
extern "C" void kernel_launch(void* const* d_in, const int* in_sizes, int n_in,
                              void* d_out, int out_size, void* d_ws, size_t ws_size,
                              hipStream_t stream) {
    const float* Q  = (const float*)d_in[0];
    const float* K  = (const float*)d_in[1];
    const float* V  = (const float*)d_in[2];
    const float* Wq = (const float*)d_in[3];
    const float* bq = (const float*)d_in[4];
    const float* Wk = (const float*)d_in[5];
    const float* bk = (const float*)d_in[6];
    const float* Wv = (const float*)d_in[7];
    const float* bv = (const float*)d_in[8];
    const float* Wo = (const float*)d_in[9];
    const float* bo = (const float*)d_in[10];

    const size_t PLANE  = (size_t)MROWS * DMODEL;     // 4 Mi elements
    const size_t WPLANE = (size_t)DMODEL * DMODEL;

    unsigned short* Aspl = (unsigned short*)d_ws;      // 3*PLANE us
    unsigned short* Wp   = Aspl + 3 * PLANE;           // 3*WPLANE us
    unsigned short* q3   = Wp + 3 * WPLANE;            // 3*PLANE us
    unsigned short* k3   = q3 + 3 * PLANE;             // 3*PLANE us
    float*          vf   = (float*)(k3 + 3 * PLANE);   // PLANE f32
    unsigned short* attnb = Aspl;   // reuse after V-proj consumed Aspl

    dim3 blk(256, 1, 1);
    dim3 gg(DMODEL / 64, MROWS / 64, 1);
    dim3 gw(DMODEL / 64, DMODEL / 64, 1);
    const int nvec = (int)(PLANE / 8);
    dim3 gs((nvec + 255) / 256, 1, 1);

    // ---- Q projection -> split planes (scaled 1/8) ----
    splitx_k<3><<<gs, blk, 0, stream>>>(Q, Aspl, nvec, PLANE);
    wsplit_k<3><<<gw, blk, 0, stream>>>(Wq, Wp, WPLANE);
    gemm_planes<3, true, true><<<gg, blk, 0, stream>>>(Aspl, Wp, bq, nullptr, q3, 0.125f,
                                                       MROWS, DMODEL, DMODEL, PLANE, WPLANE, PLANE);
    // ---- K projection -> split planes ----
    splitx_k<3><<<gs, blk, 0, stream>>>(K, Aspl, nvec, PLANE);
    wsplit_k<3><<<gw, blk, 0, stream>>>(Wk, Wp, WPLANE);
    gemm_planes<3, true, true><<<gg, blk, 0, stream>>>(Aspl, Wp, bk, nullptr, k3, 1.0f,
                                                       MROWS, DMODEL, DMODEL, PLANE, WPLANE, PLANE);
    // ---- V projection (plain bf16 MFMA) -> fp32 vf ----
    splitx_k<1><<<gs, blk, 0, stream>>>(V, Aspl, nvec, PLANE);
    wsplit_k<1><<<gw, blk, 0, stream>>>(Wv, Wp, WPLANE);
    gemm_planes<1, false, false><<<gg, blk, 0, stream>>>(Aspl, Wp, bv, vf, nullptr, 1.0f,
                                                         MROWS, DMODEL, DMODEL, PLANE, WPLANE, PLANE);
    // ---- fused masked attention (single pass) -> bf16 attnb ----
    attn_k<<<dim3(64 * 16, 1, 1), blk, 0, stream>>>(q3, k3, vf, attnb, PLANE);

    // ---- O projection (plain bf16 MFMA) -> fp32 d_out ----
    wsplit_k<1><<<gw, blk, 0, stream>>>(Wo, Wp, WPLANE);
    gemm_planes<1, false, false><<<gg, blk, 0, stream>>>(attnb, Wp, bo, (float*)d_out, nullptr, 1.0f,
                                                         MROWS, DMODEL, DMODEL, PLANE, WPLANE, PLANE);
}